// Round 5
// baseline (497.768 us; speedup 1.0000x reference)
//
#include <hip/hip_runtime.h>
#include <hip/hip_bf16.h>

#define NN 4096     // layer size n
#define RR 4        // displacement rank
#define BB 8192     // batch
#define CHUNK 64            // t-chunk for prefix kernels
#define NCHUNK (NN / CHUNK) // 64

typedef __bf16 bf16x8 __attribute__((ext_vector_type(8)));
typedef float f32x4 __attribute__((ext_vector_type(4)));
typedef unsigned short u16;
typedef unsigned int u32;

#define GLOBAL_AS(p) ((const __attribute__((address_space(1))) u32*)(p))
#define LDS_AS(p) ((__attribute__((address_space(3))) u32*)(p))

__device__ inline u32 pack_bf2(float lo, float hi) {
    __hip_bfloat162 h2 = __float22bfloat162_rn(make_float2(lo, hi));
    return *(u32*)&h2;
}

// ---------------------------------------------------------------------------
// Kernel 0: cast x (f32 row-major) -> bf16 row-major. Pure streaming.
// ---------------------------------------------------------------------------
__global__ __launch_bounds__(256) void cast_x_kernel(const float* __restrict__ x,
                                                     u16* __restrict__ xbf) {
    size_t i = (size_t)blockIdx.x * 256 + threadIdx.x;  // one 8-elem chunk each
    const float4* x4 = (const float4*)x;
    float4 a = x4[i * 2], b = x4[i * 2 + 1];
    uint4 o = make_uint4(pack_bf2(a.x, a.y), pack_bf2(a.z, a.w),
                         pack_bf2(b.x, b.y), pack_bf2(b.z, b.w));
    *(uint4*)(xbf + i * 8) = o;
}

// ---------------------------------------------------------------------------
// Kernel 1: block sums S_T(J,d) = sum_{t in chunk J} q(d,t)
// ---------------------------------------------------------------------------
__global__ void ksum_kernel(const float* __restrict__ G, const float* __restrict__ H,
                            float* __restrict__ S_T) {
    int dblk = blockIdx.x & 15;
    int J = blockIdx.x >> 4;
    int d = dblk * 256 + threadIdx.x;
    int t0 = J * CHUNK;
    float acc = 0.f;
#pragma unroll 4
    for (int tt = 0; tt < CHUNK; ++tt) {
        int t = t0 + tt;
        float h0 = H[t], h1 = H[NN + t], h2 = H[2 * NN + t], h3 = H[3 * NN + t];
        int idx = (d + t) & (NN - 1);
        acc += G[idx] * h0 + G[NN + idx] * h1 + G[2 * NN + idx] * h2 + G[3 * NN + idx] * h3;
    }
    S_T[J * NN + d] = acc;
}

// ---------------------------------------------------------------------------
// Kernel 2: prefix + W write (bf16 row-major) via LDS tile transpose.
// ---------------------------------------------------------------------------
__global__ __launch_bounds__(128) void kprefix_kernel(const float* __restrict__ G,
                                                      const float* __restrict__ H,
                                                      const float* __restrict__ S_T,
                                                      u16* __restrict__ W) {
    __shared__ u32 tile32[64 * 33];          // row stride 33 u32 = 66 u16
    u16* tile = (u16*)tile32;

    int itile = blockIdx.x >> 6;             // 64 row-tiles
    int J = blockIdx.x & 63;                 // 64 col-chunks
    int i0 = itile * 64, t0 = J * CHUNK;
    int dl = threadIdx.x;                    // 0..127
    int d = (i0 - t0 - 63 + dl) & (NN - 1);

    float pre = 0.f, tot = 0.f;
    for (int Jp = 0; Jp < NCHUNK; ++Jp) {
        float v = S_T[Jp * NN + d];
        if (Jp < J) pre += v;
        tot += v;
    }
    float acc = pre - 0.5f * tot;

#pragma unroll 4
    for (int tt = 0; tt < CHUNK; ++tt) {
        int t = t0 + tt;
        float h0 = H[t], h1 = H[NN + t], h2 = H[2 * NN + t], h3 = H[3 * NN + t];
        int idx = (d + t) & (NN - 1);
        acc += G[idx] * h0 + G[NN + idx] * h1 + G[2 * NN + idx] * h2 + G[3 * NN + idx] * h3;
        int r = dl + tt - 63;                // in-tile row
        if ((unsigned)r < 64u) {
            __hip_bfloat16 w = __float2bfloat16(acc);
            tile[r * 66 + tt] = *(u16*)&w;
        }
    }
    __syncthreads();

    // flush row-major: 16 rows/pass, 8 x 16B per row
    int r = threadIdx.x >> 3;                // 0..15
    int c8 = threadIdx.x & 7;
#pragma unroll
    for (int pass = 0; pass < 4; ++pass) {
        int rr = pass * 16 + r;
        const u32* s = &tile32[rr * 33 + c8 * 4];
        uint4 v = make_uint4(s[0], s[1], s[2], s[3]);
        *(uint4*)(W + (size_t)(i0 + rr) * NN + t0 + c8 * 8) = v;
    }
}

// ---------------------------------------------------------------------------
// Kernel 3: NT GEMM  y[b,i] = sum_j xbf[b,j] * W[i,j]  (f32 out)
// 256x256 tile, BK=64, 8 waves (2M x 4N).
// R4 diagnosis: LDS-read time (2259 cyc/K-tile/CU) and MFMA time (2483) were
// EXACTLY serialized (wall 4762) because reads bunch before each barrier --
// each wave's operands sit deep in the CU LDS FIFO, so first-MFMA readiness
// ~= full drain, regardless of phase granularity or fences (R1/R2/R3/R4).
//
// R5 structure: CONSUMPTION-ORDERED READ/MFMA PIPELINE, one barrier per tile.
// Per K-tile: segments S0..S8 (2-6 ds_reads each) interleaved with MFMA
// blocks B0..B8 (4-8 MFMAs) such that Bk's operands were read in S(k-1) or
// earlier (<=4 reads outstanding when Bk issues -> compiler-counted lgkm,
// LDS drains under MFMA execution). sched_group_barrier pins the interleave
// (hipcc otherwise re-clusters all loads to the front = R4 behavior).
// Steady state per 8-MFMA block per CU: matrix 310 cyc vs LDS 190 -> matrix-
// bound; predicted wall/tile ~= 400 startup + 2483 MFMA.
//
// Sync ledger (one vmcnt(0) + one s_barrier per tile):
//  - stages for tile i+1 (opposite LDS parity) issue at tile-i START;
//    vmcnt(0) at tile-i END drains them with ~full-tile issue distance
//    (~3000 cyc >> HBM latency) -> near-free drain, unlike stage-late+drain.
//  - barrier at tile end: all waves' reads of par p done before any wave's
//    tile-i+1 stages (which target par p^1 anyway) and before tile-i+2
//    stages (par p) issued during tile i+1. RAW: reads of par q at tile i+1
//    only after ALL waves' vmcnt(0) retired (barrier) -> all writes landed.
//  - within a tile, reads touch par p only, stages write par p^1 only ->
//    no intra-tile cross-wave hazard; no inner barriers needed.
// ---------------------------------------------------------------------------

#define ST_A(kt, c) do { \
    const u16* s_ = srcA + (size_t)(c) * (64 * NN) + (size_t)(kt) * 64; \
    char* d_ = (char*)As + (((kt) & 1) * 32768) + ((c) * 8192) + t16; \
    __builtin_amdgcn_global_load_lds(GLOBAL_AS(s_), LDS_AS(d_), 16, 0, 0); \
    __builtin_amdgcn_global_load_lds(GLOBAL_AS(s_ + (size_t)128 * NN), LDS_AS(d_ + 16384), 16, 0, 0); \
} while (0)

#define ST_B(kt, hb) do { \
    const u16* s_ = srcB + (size_t)(hb) * (128 * NN) + (size_t)(kt) * 64; \
    char* d_ = (char*)Bs + (((kt) & 1) * 32768) + ((hb) * 16384) + t16; \
    __builtin_amdgcn_global_load_lds(GLOBAL_AS(s_), LDS_AS(d_), 16, 0, 0); \
    __builtin_amdgcn_global_load_lds(GLOBAL_AS(s_ + (size_t)64 * NN), LDS_AS(d_ + 8192), 16, 0, 0); \
} while (0)

#define SGB __builtin_amdgcn_sched_group_barrier
#define SG_DS(n) SGB(0x100, n, 0)   /* DS_READ  */
#define SG_MM(n) SGB(0x008, n, 0)   /* MFMA     */
#define SG_VM(n) SGB(0x030, n, 0)   /* VMEM(_READ): the global_load_lds */

// full-tile stage: 8 global_load_lds (A chunks 0,1 + B halves 0,1), pinned
#define ST_TILE(kt) do { \
    ST_A(kt, 0); ST_A(kt, 1); ST_B(kt, 0); ST_B(kt, 1); SG_VM(8); \
} while (0)

#define AFR(cp, mi, ks) (*(const bf16x8*)(Abase + (cp) * 32768 + (mi) * 2048 + (sx ^ ((ks) << 6))))
#define BFR(cp, ni, ks) (*(const bf16x8*)(Bbase + (cp) * 32768 + (ni) * 2048 + (sx ^ ((ks) << 6))))

#define MFMA_(a, b, c) __builtin_amdgcn_mfma_f32_16x16x32_bf16(a, b, c, 0, 0, 0)

#define MMe(mi, ni) do { \
    acc[mi][ni] = MFMA_(xe0, bq[2 * (ni)], acc[mi][ni]); \
    acc[mi][ni] = MFMA_(xe1, bq[2 * (ni) + 1], acc[mi][ni]); \
} while (0)
#define MMo(mi, ni) do { \
    acc[mi][ni] = MFMA_(xo0, bq[2 * (ni)], acc[mi][ni]); \
    acc[mi][ni] = MFMA_(xo1, bq[2 * (ni) + 1], acc[mi][ni]); \
} while (0)

#define VMC(n) asm volatile("s_waitcnt vmcnt(" #n ")" ::: "memory")

// One K-tile: STAGE (next tile) -> consumption-ordered read/MFMA pipeline ->
// vmcnt(0) -> barrier.  Read segments one block ahead of their consumers.
#define TILE_BODY(cp, STAGE) do { \
    STAGE; \
    /* S0: operands for B0 (+ xa of mi0) */ \
    bq[0] = BFR(cp, 0, 0); bq[1] = BFR(cp, 0, 1); \
    xe0 = AFR(cp, 0, 0);   xe1 = AFR(cp, 0, 1); \
    bq[2] = BFR(cp, 1, 0); bq[3] = BFR(cp, 1, 1); SG_DS(6); \
    /* S1: bq hi half (for B1) */ \
    bq[4] = BFR(cp, 2, 0); bq[5] = BFR(cp, 2, 1); \
    bq[6] = BFR(cp, 3, 0); bq[7] = BFR(cp, 3, 1); SG_DS(4); \
    /* B0: mi0 x ni0,1 */  MMe(0, 0); MMe(0, 1); SG_MM(4); \
    /* S2: mi1 */          xo0 = AFR(cp, 1, 0); xo1 = AFR(cp, 1, 1); SG_DS(2); \
    /* B1: mi0 x ni2,3 */  MMe(0, 2); MMe(0, 3); SG_MM(4); \
    /* S3: mi2 */          xe0 = AFR(cp, 2, 0); xe1 = AFR(cp, 2, 1); SG_DS(2); \
    /* B2: mi1 */          MMo(1, 0); MMo(1, 1); MMo(1, 2); MMo(1, 3); SG_MM(8); \
    /* S4: mi3 */          xo0 = AFR(cp, 3, 0); xo1 = AFR(cp, 3, 1); SG_DS(2); \
    /* B3: mi2 */          MMe(2, 0); MMe(2, 1); MMe(2, 2); MMe(2, 3); SG_MM(8); \
    /* S5: mi4 */          xe0 = AFR(cp, 4, 0); xe1 = AFR(cp, 4, 1); SG_DS(2); \
    /* B4: mi3 */          MMo(3, 0); MMo(3, 1); MMo(3, 2); MMo(3, 3); SG_MM(8); \
    /* S6: mi5 */          xo0 = AFR(cp, 5, 0); xo1 = AFR(cp, 5, 1); SG_DS(2); \
    /* B5: mi4 */          MMe(4, 0); MMe(4, 1); MMe(4, 2); MMe(4, 3); SG_MM(8); \
    /* S7: mi6 */          xe0 = AFR(cp, 6, 0); xe1 = AFR(cp, 6, 1); SG_DS(2); \
    /* B6: mi5 */          MMo(5, 0); MMo(5, 1); MMo(5, 2); MMo(5, 3); SG_MM(8); \
    /* S8: mi7 */          xo0 = AFR(cp, 7, 0); xo1 = AFR(cp, 7, 1); SG_DS(2); \
    /* B7: mi6 */          MMe(6, 0); MMe(6, 1); MMe(6, 2); MMe(6, 3); SG_MM(8); \
    /* B8: mi7 */          MMo(7, 0); MMo(7, 1); MMo(7, 2); MMo(7, 3); SG_MM(8); \
    VMC(0); \
    __builtin_amdgcn_s_barrier(); \
} while (0)

__global__ __launch_bounds__(512, 2) void gemm256_kernel(const u16* __restrict__ At,
                                                         const u16* __restrict__ Bt,
                                                         float* __restrict__ C) {
    __shared__ __align__(16) u16 As[2][2][2][64][64];  // 64 KiB
    __shared__ __align__(16) u16 Bs[2][2][2][64][64];  // 64 KiB

    // T1: XCD-aware swizzle; nwg = 512, 512 % 8 == 0 -> simple bijection
    int bid = blockIdx.x;
    int swz = (bid & 7) * 64 + (bid >> 3);
    int bx = swz & 15, by = swz >> 4;       // each XCD: 4 M-panels x all 16 N
    int m0 = by * 256, n0 = bx * 256;

    int t = threadIdx.x;
    int lane = t & 63, wave = t >> 6;
    int wm = wave >> 2, wn = wave & 3;      // 2M x 4N waves; per-wave C: 128x64
    int lrow = lane & 15, lq = lane >> 4;

    // staging: thread t covers linear LDS bytes [t*16); source col pre-swizzled
    int rowt = t >> 3;                                  // 0..63
    int colel = ((t & 7) ^ (rowt & 7)) << 3;            // element offset
    const u16* srcA = At + (size_t)(m0 + rowt) * NN + colel;
    const u16* srcB = Bt + (size_t)(n0 + rowt) * NN + colel;
    int t16 = t * 16;

    // ds_read bases (swizzled): frag byte = row*128 + ((lq<<4 | ks<<6) ^ ((row&7)<<4))
    const char* Abase = (const char*)As + wm * 16384 + lrow * 128;
    const char* Bbase = (const char*)Bs + (wn >> 1) * 16384 + (wn & 1) * 8192 + lrow * 128;
    int sx = (lq << 4) ^ ((lrow & 7) << 4);

    f32x4 acc[8][4] = {};
    bf16x8 bq[8], xe0, xe1, xo0, xo1;

    // prologue: stage K-tile 0, drain, sync
    ST_TILE(0);
    VMC(0);
    __builtin_amdgcn_s_barrier();

#pragma unroll 1
    for (int j = 0; j < 31; ++j) {
        int k0 = 2 * j;
        TILE_BODY(0, ST_TILE(k0 + 1));
        TILE_BODY(1, ST_TILE(k0 + 2));
    }
    // tail: tile 62 stages 63; tile 63 stages nothing
    TILE_BODY(0, ST_TILE(63));
    TILE_BODY(1, );

    // epilogue: D layout col=lane&15, row=(lane>>4)*4+e
#pragma unroll
    for (int mi = 0; mi < 8; ++mi)
#pragma unroll
        for (int ni = 0; ni < 4; ++ni)
#pragma unroll
            for (int e = 0; e < 4; ++e) {
                int row = m0 + wm * 128 + mi * 16 + lq * 4 + e;
                int col = n0 + wn * 64 + ni * 16 + lrow;
                C[(size_t)row * NN + col] = acc[mi][ni][e];
            }
}

// ---------------------------------------------------------------------------
extern "C" void kernel_launch(void* const* d_in, const int* in_sizes, int n_in,
                              void* d_out, int out_size, void* d_ws, size_t ws_size,
                              hipStream_t stream) {
    const float* x = (const float*)d_in[0];
    const float* G = (const float*)d_in[1];
    const float* H = (const float*)d_in[2];
    float* y = (float*)d_out;

    char* ws = (char*)d_ws;
    u16* xbf = (u16*)ws;                                   // 64 MB, row-major
    u16* Wbf = (u16*)(ws + (size_t)BB * NN * 2);           // 32 MB, row-major
    float* S_T = (float*)(ws + (size_t)BB * NN * 2 + (size_t)NN * NN * 2);  // 1 MB

    hipLaunchKernelGGL(cast_x_kernel, dim3((size_t)BB * NN / 8 / 256), dim3(256), 0, stream,
                       x, xbf);
    hipLaunchKernelGGL(ksum_kernel, dim3((NN / 256) * NCHUNK), dim3(256), 0, stream, G, H, S_T);
    hipLaunchKernelGGL(kprefix_kernel, dim3(64 * 64), dim3(128), 0, stream, G, H, S_T, Wbf);
    hipLaunchKernelGGL(gemm256_kernel, dim3((BB / 256) * (NN / 256)), dim3(512), 0, stream,
                       xbf, Wbf, y);
}